// Round 7
// baseline (267.689 us; speedup 1.0000x reference)
//
#include <hip/hip_runtime.h>
#include <hip/hip_bf16.h>

// Problem constants (match reference)
#define D_MODEL 1024
#define N_HEADS 16
#define HEAD_DIM 64
#define SEQ_T 2048
#define BATCH 4

#define SL2E 0.18033688011f   // 0.125 * log2(e), baked into Q at GEMM epilogue

typedef short s8v  __attribute__((ext_vector_type(8)));   // 8 x bf16 bits
typedef float f32x4 __attribute__((ext_vector_type(4)));
typedef unsigned long long ull;

static __device__ __forceinline__ unsigned int fbits(float f) {
  union { float f; unsigned int u; } v; v.f = f; return v.u;
}
static __device__ __forceinline__ unsigned short f2bf(float f) {
  unsigned int u = fbits(f);
  return (unsigned short)((u + 0x7FFF + ((u >> 16) & 1)) >> 16);  // RNE
}

// pack 2 f32 -> 2 bf16 in one dword (lo=a, hi=b)
#if __has_builtin(__builtin_amdgcn_cvt_pk_bf16_f32)
typedef __bf16 bf2 __attribute__((ext_vector_type(2)));
static __device__ __forceinline__ unsigned int pk2bf(float a, float b) {
  union { bf2 v; unsigned int u; } u;
  u.v = __builtin_amdgcn_cvt_pk_bf16_f32(a, b);
  return u.u;
}
#else
static __device__ __forceinline__ unsigned int pk2bf(float a, float b) {
  return ((fbits(a) + 0x8000u) >> 16) | ((fbits(b) + 0x8000u) & 0xFFFF0000u);
}
#endif

// async global->LDS, 16B per lane; LDS dest = wave-uniform base + lane*16
static __device__ __forceinline__ void glds16(const void* g, void* l) {
  __builtin_amdgcn_global_load_lds(
      (const __attribute__((address_space(1))) void*)g,
      (__attribute__((address_space(3))) void*)l, 16, 0, 0);
}

// ---------------------------------------------------------------------------
// bf16 MFMA GEMM (m97 structure): C = A @ B + bias
//   A bf16 [M,K] rm, Bt bf16 [N,K] rm. 128x128 tile, BK=64, 4 waves.
//   OUT 0: proj, fp32, SWAPPED mfma order -> regs hold consecutive n ->
//          float4 global stores.
//   OUT 1: QK part of qkv, bf16 into qkb [M,2048], swapped -> b64 stores;
//          Q cols (bn0<1024) pre-scaled by SL2E.
//   OUT 2: V part, ORIGINAL order (regs = consecutive m) -> transposed
//          vT [bh][d][T] b64 stores.
// ---------------------------------------------------------------------------
template<int OUT>
__global__ __launch_bounds__(256) void gemm_bt_kernel(
    const unsigned short* __restrict__ A, const unsigned short* __restrict__ Bt,
    const float* __restrict__ bias, float* __restrict__ Cout,
    unsigned short* __restrict__ qkb, unsigned short* __restrict__ vT,
    int M, int N, int K, int bn_base)
{
  __shared__ unsigned short Al[128 * 64];
  __shared__ unsigned short Bl[128 * 64];

  const int tid  = threadIdx.x;
  const int lane = tid & 63;
  const int wave = tid >> 6;
  const int col  = lane & 15;
  const int quad = lane >> 4;
  const int wm   = (wave & 1) * 64;
  const int wn   = (wave >> 1) * 64;
  const int bm0  = blockIdx.y * 128;
  const int bn0  = bn_base + blockIdx.x * 128;
  const int cx   = col & 7;

  f32x4 acc[4][4];
  #pragma unroll
  for (int t = 0; t < 4; ++t)
    #pragma unroll
    for (int u = 0; u < 4; ++u) acc[t][u] = (f32x4)0.f;

  for (int k0 = 0; k0 < K; k0 += 64) {
    __syncthreads();
    #pragma unroll
    for (int i = 0; i < 4; ++i) {
      int idx = i * 256 + tid;
      int row = idx >> 3;
      int gc  = (idx & 7) ^ (row & 7);
      glds16(A  + (size_t)(bm0 + row) * K + k0 + gc * 8, &Al[idx * 8]);
      glds16(Bt + (size_t)(bn0 + row) * K + k0 + gc * 8, &Bl[idx * 8]);
    }
    __syncthreads();

    #pragma unroll
    for (int s = 0; s < 2; ++s) {
      s8v af[4], bf[4];
      #pragma unroll
      for (int t = 0; t < 4; ++t) {
        af[t] = *(const s8v*)&Al[(wm + t * 16 + col) * 64 + (((s * 4 + quad) ^ cx) * 8)];
        bf[t] = *(const s8v*)&Bl[(wn + t * 16 + col) * 64 + (((s * 4 + quad) ^ cx) * 8)];
      }
      #pragma unroll
      for (int t = 0; t < 4; ++t)
        #pragma unroll
        for (int u = 0; u < 4; ++u) {
          if (OUT == 2)
            acc[t][u] = __builtin_amdgcn_mfma_f32_16x16x32_bf16(af[t], bf[u], acc[t][u], 0, 0, 0);
          else  // swapped: C^T tile, regs = consecutive n
            acc[t][u] = __builtin_amdgcn_mfma_f32_16x16x32_bf16(bf[u], af[t], acc[t][u], 0, 0, 0);
        }
    }
  }

  if (OUT == 2) {
    // V epilogue: packed b64 stores into vT [bh][d][T] (regs = consecutive m)
    #pragma unroll
    for (int u = 0; u < 4; ++u) {
      float bv = bias[bn0 + wn + u * 16 + col];
      int hd = (bn0 + wn + u * 16 + col) - 2048;       // h*64 + d
      #pragma unroll
      for (int t = 0; t < 4; ++t) {
        int m_base = bm0 + wm + t * 16 + quad * 4;
        size_t bh = (size_t)(bm0 >> 11) * 16 + (hd >> 6);
        uint2 pk;
        pk.x = pk2bf(acc[t][u][0] + bv, acc[t][u][1] + bv);
        pk.y = pk2bf(acc[t][u][2] + bv, acc[t][u][3] + bv);
        *(uint2*)(vT + (bh * 64 + (hd & 63)) * 2048 + (m_base & 2047)) = pk;
      }
    }
  } else {
    const float sc = (OUT == 1 && bn0 < 1024) ? SL2E : 1.0f;  // Q pre-scale
    #pragma unroll
    for (int u = 0; u < 4; ++u) {
      int n_base = bn0 + wn + u * 16 + quad * 4;
      float4 b4 = *(const float4*)&bias[n_base];
      #pragma unroll
      for (int t = 0; t < 4; ++t) {
        size_t m = bm0 + wm + t * 16 + col;
        float v0 = (acc[t][u][0] + b4.x) * sc, v1 = (acc[t][u][1] + b4.y) * sc;
        float v2 = (acc[t][u][2] + b4.z) * sc, v3 = (acc[t][u][3] + b4.w) * sc;
        if (OUT == 0) {
          float4 o = {v0, v1, v2, v3};
          *(float4*)(Cout + m * N + n_base) = o;
        } else {
          uint2 pk = {pk2bf(v0, v1), pk2bf(v2, v3)};
          *(uint2*)(qkb + m * 2048 + n_base) = pk;
        }
      }
    }
  }
}

// ---------------------------------------------------------------------------
// Merged prep: x cast (blocks 0..8191), W_qkv transpose (8192..11263),
// W_proj transpose (11264..12287).
// ---------------------------------------------------------------------------
static __device__ __forceinline__ void transpose_tile(
    const float* __restrict__ W, unsigned short* __restrict__ Wt,
    int K, int N, int n0, int k0)
{
  __shared__ float tile[32][33];
  const int tx = threadIdx.x & 31, ty = threadIdx.x >> 5;
  #pragma unroll
  for (int i = 0; i < 4; ++i)
    tile[ty + i * 8][tx] = W[(size_t)(k0 + ty + i * 8) * N + n0 + tx];
  __syncthreads();
  #pragma unroll
  for (int i = 0; i < 4; ++i)
    Wt[(size_t)(n0 + ty + i * 8) * K + k0 + tx] = f2bf(tile[tx][ty + i * 8]);
}

__global__ __launch_bounds__(256) void prep_kernel(
    const float* __restrict__ x, const float* __restrict__ W_qkv,
    const float* __restrict__ W_proj, uint2* __restrict__ xb,
    unsigned short* __restrict__ wqt, unsigned short* __restrict__ wpt)
{
  const int bid = blockIdx.x;
  if (bid < 8192) {
    int i = bid * 256 + threadIdx.x;
    float4 v = ((const float4*)x)[i];
    uint2 o = {pk2bf(v.x, v.y), pk2bf(v.z, v.w)};
    xb[i] = o;
  } else if (bid < 8192 + 3072) {
    int b2 = bid - 8192;                      // W_qkv [1024, 3072] -> wqt
    transpose_tile(W_qkv, wqt, 1024, 3072, (b2 % 96) * 32, (b2 / 96) * 32);
  } else {
    int b3 = bid - 11264;                     // W_proj [1024, 1024] -> wpt
    transpose_tile(W_proj, wpt, 1024, 1024, (b3 % 32) * 32, (b3 / 32) * 32);
  }
}

// ---------------------------------------------------------------------------
// bf16 MFMA flash causal attention, QT=128, KT=64, async dbuf, fixed-max
// softmax, S^T formulation (S^T = K·Q^T; lane holds k=quad*4+r, q=col).
//   - Row sums via ones-MFMA: mfma(ones, pf) broadcasts sum(q=col) to all
//     lanes (no adds, no epilogue shuffles). Sum uses packed bf16 P — exactly
//     matches the PV numerator.
//   - P packed with v_cvt_pk_bf16_f32, stored in XOR-chunk-swizzled Ps
//     (stride 64, GEMM-verified conflict-free pattern).
//   - PV swapped: mfma(vf, pf) -> O^T (regs = consecutive d) -> b64 y stores.
// Grid: (B*H, T/128), qblk reversed (LPT). 4 waves; wave w owns stripes
// q0+w*16 and q0+64+w*16.
// ---------------------------------------------------------------------------
__global__ __launch_bounds__(256, 3) void attn_mfma_kernel(
    const unsigned short* __restrict__ qk, const unsigned short* __restrict__ vT,
    unsigned short* __restrict__ y)
{
  __shared__ unsigned short Ks[2][64 * 64];
  __shared__ unsigned short Vs[2][64 * 64];
  __shared__ unsigned short Ps[128 * 64];

  const int tid  = threadIdx.x;
  const int wave = tid >> 6;
  const int lane = tid & 63;
  const int col  = lane & 15;
  const int quad = lane >> 4;
  const int cx   = col & 7;

  const int bh = blockIdx.x;
  const int b = bh >> 4, h = bh & 15;
  const int qblk = 15 - (int)blockIdx.y;     // LPT: long blocks first
  const int q0 = qblk * 128;
  const int nk = 2 * qblk + 2;
  const int C2 = 2048;

  const unsigned short* qbase = qk + (size_t)b * SEQ_T * C2 + h * 64;
  const unsigned short* kbase = qbase + 1024;
  const unsigned short* vbase = vT + (size_t)bh * 64 * 2048;

  s8v ones;
  #pragma unroll
  for (int j = 0; j < 8; ++j) ones[j] = (short)0x3F80;   // bf16 1.0

  // Q fragments for both stripes (rows of Q, pre-scaled by SL2E)
  s8v qf[2][2];
  #pragma unroll
  for (int s = 0; s < 2; ++s)
    #pragma unroll
    for (int c = 0; c < 2; ++c)
      qf[s][c] = *(const s8v*)(qbase +
          (size_t)(q0 + s * 64 + wave * 16 + col) * C2 + c * 32 + quad * 8);

  f32x4 acc[2][4];                 // O^T: [stripe][d-tile], regs = consecutive d
  f32x4 accL[2];                   // row-sum broadcast accumulator
  #pragma unroll
  for (int s = 0; s < 2; ++s) {
    accL[s] = (f32x4)0.f;
    #pragma unroll
    for (int t = 0; t < 4; ++t) acc[s][t] = (f32x4)0.f;
  }

  auto stage = [&](int kt, int bi) {
    const int k0 = kt * 64;
    #pragma unroll
    for (int i = 0; i < 2; ++i) {
      int cid = (i * 4 + wave) * 64 + lane;
      int row = cid >> 3;
      int gc  = (cid & 7) ^ (row & 7);        // XOR k-chunk swizzle
      glds16(kbase + (size_t)(k0 + row) * C2 + gc * 8, &Ks[bi][cid * 8]);
      glds16(vbase + (size_t)row * 2048 + k0 + gc * 8, &Vs[bi][cid * 8]);
    }
  };

  auto tile_body = [&](int kt, int bi) {
    const int k0 = kt * 64;
    const int psrow = wave * 16 + col;        // + s*64

    // K fragments (rows of K)
    s8v kf[4][2];
    #pragma unroll
    for (int t = 0; t < 4; ++t)
      #pragma unroll
      for (int c = 0; c < 2; ++c)
        kf[t][c] = *(const s8v*)&Ks[bi][(t * 16 + col) * 64 + (((c * 4 + quad) ^ cx) * 8)];

    #pragma unroll
    for (int s = 0; s < 2; ++s) {
      const int qs = q0 + s * 64 + wave * 16;
      if (k0 > qs + 15) continue;             // stripe fully masked

      // S^T = K·Q^T : lane holds S^T[k0 + t*16 + quad*4 + r][qs + col]
      f32x4 st[4];
      #pragma unroll
      for (int t = 0; t < 4; ++t) st[t] = (f32x4)0.f;
      #pragma unroll
      for (int t = 0; t < 4; ++t)
        #pragma unroll
        for (int c = 0; c < 2; ++c)
          st[t] = __builtin_amdgcn_mfma_f32_16x16x32_bf16(kf[t][c], qf[s][c], st[t], 0, 0, 0);

      const bool diag = (k0 + 63 > qs);       // wave-uniform
      const int qg = qs + col;
      #pragma unroll
      for (int t = 0; t < 4; ++t) {
        float e[4];
        #pragma unroll
        for (int r = 0; r < 4; ++r) {
          float v = exp2f(st[t][r]);
          if (diag && (k0 + t * 16 + quad * 4 + r > qg)) v = 0.f;
          e[r] = v;
        }
        uint2 pk = {pk2bf(e[0], e[1]), pk2bf(e[2], e[3])};
        *(uint2*)&Ps[(s * 64 + psrow) * 64 +
                     (((2 * t + (quad >> 1)) ^ cx) * 8) + (quad & 1) * 4] = pk;
      }
    }

    // V^T fragments (rows of V^T), then sum-MFMA + O^T += V^T·P^T per stripe
    s8v vf[4][2];
    #pragma unroll
    for (int t = 0; t < 4; ++t)
      #pragma unroll
      for (int c = 0; c < 2; ++c)
        vf[t][c] = *(const s8v*)&Vs[bi][(t * 16 + col) * 64 + (((c * 4 + quad) ^ cx) * 8)];
    #pragma unroll
    for (int s = 0; s < 2; ++s) {
      const int qs = q0 + s * 64 + wave * 16;
      if (k0 > qs + 15) continue;
      s8v pf[2];
      #pragma unroll
      for (int c = 0; c < 2; ++c)
        pf[c] = *(const s8v*)&Ps[(s * 64 + psrow) * 64 + (((c * 4 + quad) ^ cx) * 8)];
      #pragma unroll
      for (int c = 0; c < 2; ++c)
        accL[s] = __builtin_amdgcn_mfma_f32_16x16x32_bf16(ones, pf[c], accL[s], 0, 0, 0);
      #pragma unroll
      for (int t = 0; t < 4; ++t)
        #pragma unroll
        for (int c = 0; c < 2; ++c)
          acc[s][t] = __builtin_amdgcn_mfma_f32_16x16x32_bf16(vf[t][c], pf[c], acc[s][t], 0, 0, 0);
    }
  };

  stage(0, 0);
  for (int kt = 0; kt < nk; kt += 2) {
    __syncthreads();                               // buf0 staged & visible
    if (kt + 1 < nk) stage(kt + 1, 1);             // prefetch overlaps compute
    tile_body(kt, 0);
    if (kt + 1 < nk) {
      __syncthreads();                             // buf1 staged & visible
      if (kt + 2 < nk) stage(kt + 2, 0);
      tile_body(kt + 1, 1);
    }
  }

  // epilogue: sum is broadcast in accL (all regs equal); b64 y stores along d
  #pragma unroll
  for (int s = 0; s < 2; ++s) {
    float inv = 1.0f / accL[s][0];
    int q = q0 + s * 64 + wave * 16 + col;
    unsigned short* yrow = y + (size_t)(b * SEQ_T + q) * D_MODEL + h * 64 + quad * 4;
    #pragma unroll
    for (int t = 0; t < 4; ++t) {
      uint2 pk = {pk2bf(acc[s][t][0] * inv, acc[s][t][1] * inv),
                  pk2bf(acc[s][t][2] * inv, acc[s][t][3] * inv)};
      *(uint2*)(yrow + t * 16) = pk;
    }
  }
}

// ---------------------------------------------------------------------------
extern "C" void kernel_launch(void* const* d_in, const int* in_sizes, int n_in,
                              void* d_out, int out_size, void* d_ws, size_t ws_size,
                              hipStream_t stream) {
  const float* x      = (const float*)d_in[0];
  const float* W_qkv  = (const float*)d_in[1];
  const float* b_qkv  = (const float*)d_in[2];
  const float* W_proj = (const float*)d_in[3];
  const float* b_proj = (const float*)d_in[4];
  float* out = (float*)d_out;

  const int M  = BATCH * SEQ_T;    // 8192
  const int C  = D_MODEL;          // 1024
  const int C3 = 3 * D_MODEL;      // 3072

  // workspace (bf16 = unsigned short), total ~88 MB
  unsigned short* xb  = (unsigned short*)d_ws;           // [M, C]      16 MB
  unsigned short* wqt = xb  + (size_t)M * C;             // [3C, C]      6 MB
  unsigned short* wpt = wqt + (size_t)C3 * C;            // [C, C]       2 MB
  unsigned short* qkb = wpt + (size_t)C * C;             // [M, 2C]     32 MB
  unsigned short* vTb = qkb + (size_t)M * 2 * C;         // [64,64,T]   16 MB
  unsigned short* yb  = vTb + (size_t)64 * 64 * SEQ_T;   // [M, C]      16 MB

  dim3 blk(256);

  // 0) merged prep: cast x, transpose-cast both weights
  prep_kernel<<<dim3(8192 + 3072 + 1024), blk, 0, stream>>>(
      x, W_qkv, W_proj, (uint2*)xb, wqt, wpt);

  // 1a) Q,K -> qkb [M,2048] (swapped order, b64 stores; Q pre-scaled)
  gemm_bt_kernel<1><<<dim3(16, M / 128), blk, 0, stream>>>(
      xb, wqt, b_qkv, nullptr, qkb, nullptr, M, 2048, C, 0);
  // 1b) V -> vTb transposed [bh][d][T]
  gemm_bt_kernel<2><<<dim3(8, M / 128), blk, 0, stream>>>(
      xb, wqt, b_qkv, nullptr, nullptr, vTb, M, C3, C, 2048);

  // 2) causal flash attention
  attn_mfma_kernel<<<dim3(BATCH * N_HEADS, SEQ_T / 128), blk, 0, stream>>>(
      qkb, vTb, yb);

  // 3) out = y @ W_proj + b_proj (fp32, swapped order, float4 stores)
  gemm_bt_kernel<0><<<dim3(8, M / 128), blk, 0, stream>>>(
      yb, wpt, b_proj, out, nullptr, nullptr, M, C, C, 0);
}

// Round 8
// 262.268 us; speedup vs baseline: 1.0207x; 1.0207x over previous
//
#include <hip/hip_runtime.h>
#include <hip/hip_bf16.h>

// Problem constants (match reference)
#define D_MODEL 1024
#define N_HEADS 16
#define HEAD_DIM 64
#define SEQ_T 2048
#define BATCH 4

#define SL2E 0.18033688011f   // 0.125 * log2(e), baked into Q at GEMM epilogue

typedef short s8v  __attribute__((ext_vector_type(8)));   // 8 x bf16 bits
typedef float f32x4 __attribute__((ext_vector_type(4)));
typedef unsigned long long ull;

static __device__ __forceinline__ unsigned int fbits(float f) {
  union { float f; unsigned int u; } v; v.f = f; return v.u;
}
static __device__ __forceinline__ unsigned short f2bf(float f) {
  unsigned int u = fbits(f);
  return (unsigned short)((u + 0x7FFF + ((u >> 16) & 1)) >> 16);  // RNE
}

// pack 2 f32 -> 2 bf16 in one dword (lo=a, hi=b)
#if __has_builtin(__builtin_amdgcn_cvt_pk_bf16_f32)
typedef __bf16 bf2 __attribute__((ext_vector_type(2)));
static __device__ __forceinline__ unsigned int pk2bf(float a, float b) {
  union { bf2 v; unsigned int u; } u;
  u.v = __builtin_amdgcn_cvt_pk_bf16_f32(a, b);
  return u.u;
}
#else
static __device__ __forceinline__ unsigned int pk2bf(float a, float b) {
  return ((fbits(a) + 0x8000u) >> 16) | ((fbits(b) + 0x8000u) & 0xFFFF0000u);
}
#endif

// async global->LDS, 16B per lane; LDS dest = wave-uniform base + lane*16
static __device__ __forceinline__ void glds16(const void* g, void* l) {
  __builtin_amdgcn_global_load_lds(
      (const __attribute__((address_space(1))) void*)g,
      (__attribute__((address_space(3))) void*)l, 16, 0, 0);
}

// ---------------------------------------------------------------------------
// QKV GEMM (single launch, m97 structure): 128x128 tile, BK=64, 4 waves.
// Grid x: 0..15 -> QK columns (swapped mfma -> regs = consecutive n -> b64
// stores into qkb [M,2048]; Q cols pre-scaled by SL2E). 16..23 -> V columns
// (original order -> regs = consecutive m -> transposed vT [bh][d][T]).
// ---------------------------------------------------------------------------
__global__ __launch_bounds__(256) void gemm_qkv_kernel(
    const unsigned short* __restrict__ A, const unsigned short* __restrict__ Bt,
    const float* __restrict__ bias,
    unsigned short* __restrict__ qkb, unsigned short* __restrict__ vT, int K)
{
  __shared__ unsigned short Al[128 * 64];
  __shared__ unsigned short Bl[128 * 64];

  const int tid  = threadIdx.x;
  const int lane = tid & 63;
  const int wave = tid >> 6;
  const int col  = lane & 15;
  const int quad = lane >> 4;
  const int wm   = (wave & 1) * 64;
  const int wn   = (wave >> 1) * 64;
  const int bm0  = blockIdx.y * 128;
  const int bn0  = blockIdx.x * 128;
  const int cx   = col & 7;

  f32x4 acc[4][4];
  #pragma unroll
  for (int t = 0; t < 4; ++t)
    #pragma unroll
    for (int u = 0; u < 4; ++u) acc[t][u] = (f32x4)0.f;

  if (bn0 < 2048) {
    // -------- QK path: swapped mfma (C^T tile) --------
    for (int k0 = 0; k0 < K; k0 += 64) {
      __syncthreads();
      #pragma unroll
      for (int i = 0; i < 4; ++i) {
        int idx = i * 256 + tid;
        int row = idx >> 3;
        int gc  = (idx & 7) ^ (row & 7);
        glds16(A  + (size_t)(bm0 + row) * K + k0 + gc * 8, &Al[idx * 8]);
        glds16(Bt + (size_t)(bn0 + row) * K + k0 + gc * 8, &Bl[idx * 8]);
      }
      __syncthreads();
      #pragma unroll
      for (int s = 0; s < 2; ++s) {
        s8v af[4], bf[4];
        #pragma unroll
        for (int t = 0; t < 4; ++t) {
          af[t] = *(const s8v*)&Al[(wm + t * 16 + col) * 64 + (((s * 4 + quad) ^ cx) * 8)];
          bf[t] = *(const s8v*)&Bl[(wn + t * 16 + col) * 64 + (((s * 4 + quad) ^ cx) * 8)];
        }
        #pragma unroll
        for (int t = 0; t < 4; ++t)
          #pragma unroll
          for (int u = 0; u < 4; ++u)
            acc[t][u] = __builtin_amdgcn_mfma_f32_16x16x32_bf16(bf[u], af[t], acc[t][u], 0, 0, 0);
      }
    }
    const float sc = (bn0 < 1024) ? SL2E : 1.0f;  // Q pre-scale
    #pragma unroll
    for (int u = 0; u < 4; ++u) {
      int n_base = bn0 + wn + u * 16 + quad * 4;
      float4 b4 = *(const float4*)&bias[n_base];
      #pragma unroll
      for (int t = 0; t < 4; ++t) {
        size_t m = bm0 + wm + t * 16 + col;
        uint2 pk = {pk2bf((acc[t][u][0] + b4.x) * sc, (acc[t][u][1] + b4.y) * sc),
                    pk2bf((acc[t][u][2] + b4.z) * sc, (acc[t][u][3] + b4.w) * sc)};
        *(uint2*)(qkb + m * 2048 + n_base) = pk;
      }
    }
  } else {
    // -------- V path: original order (regs = consecutive m) --------
    for (int k0 = 0; k0 < K; k0 += 64) {
      __syncthreads();
      #pragma unroll
      for (int i = 0; i < 4; ++i) {
        int idx = i * 256 + tid;
        int row = idx >> 3;
        int gc  = (idx & 7) ^ (row & 7);
        glds16(A  + (size_t)(bm0 + row) * K + k0 + gc * 8, &Al[idx * 8]);
        glds16(Bt + (size_t)(bn0 + row) * K + k0 + gc * 8, &Bl[idx * 8]);
      }
      __syncthreads();
      #pragma unroll
      for (int s = 0; s < 2; ++s) {
        s8v af[4], bf[4];
        #pragma unroll
        for (int t = 0; t < 4; ++t) {
          af[t] = *(const s8v*)&Al[(wm + t * 16 + col) * 64 + (((s * 4 + quad) ^ cx) * 8)];
          bf[t] = *(const s8v*)&Bl[(wn + t * 16 + col) * 64 + (((s * 4 + quad) ^ cx) * 8)];
        }
        #pragma unroll
        for (int t = 0; t < 4; ++t)
          #pragma unroll
          for (int u = 0; u < 4; ++u)
            acc[t][u] = __builtin_amdgcn_mfma_f32_16x16x32_bf16(af[t], bf[u], acc[t][u], 0, 0, 0);
      }
    }
    #pragma unroll
    for (int u = 0; u < 4; ++u) {
      float bv = bias[bn0 + wn + u * 16 + col];
      int hd = (bn0 + wn + u * 16 + col) - 2048;       // h*64 + d
      #pragma unroll
      for (int t = 0; t < 4; ++t) {
        int m_base = bm0 + wm + t * 16 + quad * 4;
        size_t bh = (size_t)(bm0 >> 11) * 16 + (hd >> 6);
        uint2 pk = {pk2bf(acc[t][u][0] + bv, acc[t][u][1] + bv),
                    pk2bf(acc[t][u][2] + bv, acc[t][u][3] + bv)};
        *(uint2*)(vT + (bh * 64 + (hd & 63)) * 2048 + (m_base & 2047)) = pk;
      }
    }
  }
}

// ---------------------------------------------------------------------------
// proj GEMM: fp32 out, swapped mfma -> float4 stores.
// ---------------------------------------------------------------------------
__global__ __launch_bounds__(256) void gemm_proj_kernel(
    const unsigned short* __restrict__ A, const unsigned short* __restrict__ Bt,
    const float* __restrict__ bias, float* __restrict__ Cout, int N, int K)
{
  __shared__ unsigned short Al[128 * 64];
  __shared__ unsigned short Bl[128 * 64];

  const int tid  = threadIdx.x;
  const int lane = tid & 63;
  const int wave = tid >> 6;
  const int col  = lane & 15;
  const int quad = lane >> 4;
  const int wm   = (wave & 1) * 64;
  const int wn   = (wave >> 1) * 64;
  const int bm0  = blockIdx.y * 128;
  const int bn0  = blockIdx.x * 128;
  const int cx   = col & 7;

  f32x4 acc[4][4];
  #pragma unroll
  for (int t = 0; t < 4; ++t)
    #pragma unroll
    for (int u = 0; u < 4; ++u) acc[t][u] = (f32x4)0.f;

  for (int k0 = 0; k0 < K; k0 += 64) {
    __syncthreads();
    #pragma unroll
    for (int i = 0; i < 4; ++i) {
      int idx = i * 256 + tid;
      int row = idx >> 3;
      int gc  = (idx & 7) ^ (row & 7);
      glds16(A  + (size_t)(bm0 + row) * K + k0 + gc * 8, &Al[idx * 8]);
      glds16(Bt + (size_t)(bn0 + row) * K + k0 + gc * 8, &Bl[idx * 8]);
    }
    __syncthreads();
    #pragma unroll
    for (int s = 0; s < 2; ++s) {
      s8v af[4], bf[4];
      #pragma unroll
      for (int t = 0; t < 4; ++t) {
        af[t] = *(const s8v*)&Al[(wm + t * 16 + col) * 64 + (((s * 4 + quad) ^ cx) * 8)];
        bf[t] = *(const s8v*)&Bl[(wn + t * 16 + col) * 64 + (((s * 4 + quad) ^ cx) * 8)];
      }
      #pragma unroll
      for (int t = 0; t < 4; ++t)
        #pragma unroll
        for (int u = 0; u < 4; ++u)
          acc[t][u] = __builtin_amdgcn_mfma_f32_16x16x32_bf16(bf[u], af[t], acc[t][u], 0, 0, 0);
    }
  }

  #pragma unroll
  for (int u = 0; u < 4; ++u) {
    int n_base = bn0 + wn + u * 16 + quad * 4;
    float4 b4 = *(const float4*)&bias[n_base];
    #pragma unroll
    for (int t = 0; t < 4; ++t) {
      size_t m = bm0 + wm + t * 16 + col;
      float4 o = {acc[t][u][0] + b4.x, acc[t][u][1] + b4.y,
                  acc[t][u][2] + b4.z, acc[t][u][3] + b4.w};
      *(float4*)(Cout + m * N + n_base) = o;
    }
  }
}

// ---------------------------------------------------------------------------
// Merged prep: x cast (blocks 0..8191), W_qkv transpose (8192..11263),
// W_proj transpose (11264..12287).
// ---------------------------------------------------------------------------
static __device__ __forceinline__ void transpose_tile(
    const float* __restrict__ W, unsigned short* __restrict__ Wt,
    int K, int N, int n0, int k0)
{
  __shared__ float tile[32][33];
  const int tx = threadIdx.x & 31, ty = threadIdx.x >> 5;
  #pragma unroll
  for (int i = 0; i < 4; ++i)
    tile[ty + i * 8][tx] = W[(size_t)(k0 + ty + i * 8) * N + n0 + tx];
  __syncthreads();
  #pragma unroll
  for (int i = 0; i < 4; ++i)
    Wt[(size_t)(n0 + ty + i * 8) * K + k0 + tx] = f2bf(tile[tx][ty + i * 8]);
}

__global__ __launch_bounds__(256) void prep_kernel(
    const float* __restrict__ x, const float* __restrict__ W_qkv,
    const float* __restrict__ W_proj, uint2* __restrict__ xb,
    unsigned short* __restrict__ wqt, unsigned short* __restrict__ wpt)
{
  const int bid = blockIdx.x;
  if (bid < 8192) {
    int i = bid * 256 + threadIdx.x;
    float4 v = ((const float4*)x)[i];
    uint2 o = {pk2bf(v.x, v.y), pk2bf(v.z, v.w)};
    xb[i] = o;
  } else if (bid < 8192 + 3072) {
    int b2 = bid - 8192;                      // W_qkv [1024, 3072] -> wqt
    transpose_tile(W_qkv, wqt, 1024, 3072, (b2 % 96) * 32, (b2 / 96) * 32);
  } else {
    int b3 = bid - 11264;                     // W_proj [1024, 1024] -> wpt
    transpose_tile(W_proj, wpt, 1024, 1024, (b3 % 32) * 32, (b3 / 32) * 32);
  }
}

// ---------------------------------------------------------------------------
// bf16 MFMA flash causal attention, QT=128, KT=64, async dbuf, fixed-max
// softmax, S^T formulation (S^T = K·Q^T; lane holds k=quad*4+r, q=col).
//   - st accumulators seeded from a persistent zeroed f32x4 (no per-tile
//     zero-init instructions).
//   - staging pointers advanced incrementally (no per-tile addr rebuild).
//   - row sums via ones-MFMA broadcast; P packed v_cvt_pk_bf16_f32 into
//     XOR-swizzled Ps; PV swapped -> O^T -> b64 y stores.
// Grid: (B*H, T/128), qblk reversed (LPT).
// ---------------------------------------------------------------------------
__global__ __launch_bounds__(256, 3) void attn_mfma_kernel(
    const unsigned short* __restrict__ qk, const unsigned short* __restrict__ vT,
    unsigned short* __restrict__ y)
{
  __shared__ unsigned short Ks[2][64 * 64];
  __shared__ unsigned short Vs[2][64 * 64];
  __shared__ unsigned short Ps[128 * 64];

  const int tid  = threadIdx.x;
  const int wave = tid >> 6;
  const int lane = tid & 63;
  const int col  = lane & 15;
  const int quad = lane >> 4;
  const int cx   = col & 7;

  const int bh = blockIdx.x;
  const int b = bh >> 4, h = bh & 15;
  const int qblk = 15 - (int)blockIdx.y;     // LPT: long blocks first
  const int q0 = qblk * 128;
  const int nk = 2 * qblk + 2;
  const int C2 = 2048;

  const unsigned short* qbase = qk + (size_t)b * SEQ_T * C2 + h * 64;
  const unsigned short* vbase = vT + (size_t)bh * 64 * 2048;

  s8v ones;
  #pragma unroll
  for (int j = 0; j < 8; ++j) ones[j] = (short)0x3F80;   // bf16 1.0

  // Q fragments for both stripes (rows of Q, pre-scaled by SL2E)
  s8v qf[2][2];
  #pragma unroll
  for (int s = 0; s < 2; ++s)
    #pragma unroll
    for (int c = 0; c < 2; ++c)
      qf[s][c] = *(const s8v*)(qbase +
          (size_t)(q0 + s * 64 + wave * 16 + col) * C2 + c * 32 + quad * 8);

  f32x4 acc[2][4];                 // O^T: [stripe][d-tile], regs = consecutive d
  f32x4 accL[2];                   // row-sum broadcast accumulator
  #pragma unroll
  for (int s = 0; s < 2; ++s) {
    accL[s] = (f32x4)0.f;
    #pragma unroll
    for (int t = 0; t < 4; ++t) acc[s][t] = (f32x4)0.f;
  }
  f32x4 z4 = (f32x4)0.f;           // persistent zero seed for S-tiles

  // incremental staging pointers (advanced once per stage call)
  const int srow = ((4 * 64 + lane * 8) >> 3) >> 3;  // dummy suppress
  (void)srow;
  const int cid0 = wave * 64 + lane;                 // chunk ids i=0,1
  const int cid1 = (4 + wave) * 64 + lane;
  const int row0 = cid0 >> 3, gc0 = (cid0 & 7) ^ (row0 & 7);
  const int row1 = cid1 >> 3, gc1 = (cid1 & 7) ^ (row1 & 7);
  const unsigned short* kp0 = qbase + 1024 + (size_t)row0 * C2 + gc0 * 8;
  const unsigned short* kp1 = qbase + 1024 + (size_t)row1 * C2 + gc1 * 8;
  const unsigned short* vp0 = vbase + (size_t)row0 * 2048 + gc0 * 8;
  const unsigned short* vp1 = vbase + (size_t)row1 * 2048 + gc1 * 8;

  auto stage = [&](int bi) {
    glds16(kp0, &Ks[bi][cid0 * 8]);
    glds16(kp1, &Ks[bi][cid1 * 8]);
    glds16(vp0, &Vs[bi][cid0 * 8]);
    glds16(vp1, &Vs[bi][cid1 * 8]);
    kp0 += 64 * C2; kp1 += 64 * C2;            // next 64 K-rows
    vp0 += 64;      vp1 += 64;                 // next 64 T-columns of V^T
  };

  auto tile_body = [&](int kt, int bi) {
    const int k0 = kt * 64;
    const int psrow = wave * 16 + col;        // + s*64

    // K fragments (rows of K)
    s8v kf[4][2];
    #pragma unroll
    for (int t = 0; t < 4; ++t)
      #pragma unroll
      for (int c = 0; c < 2; ++c)
        kf[t][c] = *(const s8v*)&Ks[bi][(t * 16 + col) * 64 + (((c * 4 + quad) ^ cx) * 8)];

    #pragma unroll
    for (int s = 0; s < 2; ++s) {
      const int qs = q0 + s * 64 + wave * 16;
      if (k0 > qs + 15) continue;             // stripe fully masked

      // S^T = K·Q^T : lane holds S^T[k0 + t*16 + quad*4 + r][qs + col]
      f32x4 st[4];
      #pragma unroll
      for (int t = 0; t < 4; ++t) {
        st[t] = __builtin_amdgcn_mfma_f32_16x16x32_bf16(kf[t][0], qf[s][0], z4, 0, 0, 0);
        st[t] = __builtin_amdgcn_mfma_f32_16x16x32_bf16(kf[t][1], qf[s][1], st[t], 0, 0, 0);
      }

      const bool diag = (k0 + 63 > qs);       // wave-uniform
      const int qg = qs + col;
      #pragma unroll
      for (int t = 0; t < 4; ++t) {
        float e[4];
        #pragma unroll
        for (int r = 0; r < 4; ++r) {
          float v = exp2f(st[t][r]);
          if (diag && (k0 + t * 16 + quad * 4 + r > qg)) v = 0.f;
          e[r] = v;
        }
        uint2 pk = {pk2bf(e[0], e[1]), pk2bf(e[2], e[3])};
        *(uint2*)&Ps[(s * 64 + psrow) * 64 +
                     (((2 * t + (quad >> 1)) ^ cx) * 8) + (quad & 1) * 4] = pk;
      }
    }

    // V^T fragments (rows of V^T), then sum-MFMA + O^T += V^T·P^T per stripe
    s8v vf[4][2];
    #pragma unroll
    for (int t = 0; t < 4; ++t)
      #pragma unroll
      for (int c = 0; c < 2; ++c)
        vf[t][c] = *(const s8v*)&Vs[bi][(t * 16 + col) * 64 + (((c * 4 + quad) ^ cx) * 8)];
    #pragma unroll
    for (int s = 0; s < 2; ++s) {
      const int qs = q0 + s * 64 + wave * 16;
      if (k0 > qs + 15) continue;
      s8v pf[2];
      #pragma unroll
      for (int c = 0; c < 2; ++c)
        pf[c] = *(const s8v*)&Ps[(s * 64 + psrow) * 64 + (((c * 4 + quad) ^ cx) * 8)];
      #pragma unroll
      for (int c = 0; c < 2; ++c)
        accL[s] = __builtin_amdgcn_mfma_f32_16x16x32_bf16(ones, pf[c], accL[s], 0, 0, 0);
      #pragma unroll
      for (int t = 0; t < 4; ++t)
        #pragma unroll
        for (int c = 0; c < 2; ++c)
          acc[s][t] = __builtin_amdgcn_mfma_f32_16x16x32_bf16(vf[t][c], pf[c], acc[s][t], 0, 0, 0);
    }
  };

  stage(0);
  for (int kt = 0; kt < nk; kt += 2) {
    __syncthreads();                               // buf0 staged & visible
    if (kt + 1 < nk) stage(1);                     // prefetch overlaps compute
    tile_body(kt, 0);
    if (kt + 1 < nk) {
      __syncthreads();                             // buf1 staged & visible
      if (kt + 2 < nk) stage(0);
      tile_body(kt + 1, 1);
    }
  }

  // epilogue: sum is broadcast in accL (all regs equal); b64 y stores along d
  #pragma unroll
  for (int s = 0; s < 2; ++s) {
    float inv = 1.0f / accL[s][0];
    int q = q0 + s * 64 + wave * 16 + col;
    unsigned short* yrow = y + (size_t)(b * SEQ_T + q) * D_MODEL + h * 64 + quad * 4;
    #pragma unroll
    for (int t = 0; t < 4; ++t) {
      uint2 pk = {pk2bf(acc[s][t][0] * inv, acc[s][t][1] * inv),
                  pk2bf(acc[s][t][2] * inv, acc[s][t][3] * inv)};
      *(uint2*)(yrow + t * 16) = pk;
    }
  }
}

// ---------------------------------------------------------------------------
extern "C" void kernel_launch(void* const* d_in, const int* in_sizes, int n_in,
                              void* d_out, int out_size, void* d_ws, size_t ws_size,
                              hipStream_t stream) {
  const float* x      = (const float*)d_in[0];
  const float* W_qkv  = (const float*)d_in[1];
  const float* b_qkv  = (const float*)d_in[2];
  const float* W_proj = (const float*)d_in[3];
  const float* b_proj = (const float*)d_in[4];
  float* out = (float*)d_out;

  const int M  = BATCH * SEQ_T;    // 8192
  const int C  = D_MODEL;          // 1024
  const int C3 = 3 * D_MODEL;      // 3072

  // workspace (bf16 = unsigned short), total ~88 MB
  unsigned short* xb  = (unsigned short*)d_ws;           // [M, C]      16 MB
  unsigned short* wqt = xb  + (size_t)M * C;             // [3C, C]      6 MB
  unsigned short* wpt = wqt + (size_t)C3 * C;            // [C, C]       2 MB
  unsigned short* qkb = wpt + (size_t)C * C;             // [M, 2C]     32 MB
  unsigned short* vTb = qkb + (size_t)M * 2 * C;         // [64,64,T]   16 MB
  unsigned short* yb  = vTb + (size_t)64 * 64 * SEQ_T;   // [M, C]      16 MB

  dim3 blk(256);

  // 0) merged prep: cast x, transpose-cast both weights
  prep_kernel<<<dim3(8192 + 3072 + 1024), blk, 0, stream>>>(
      x, W_qkv, W_proj, (uint2*)xb, wqt, wpt);

  // 1) qkv GEMM (single launch): QK -> qkb; V -> vTb [bh][d][T]
  gemm_qkv_kernel<<<dim3(24, M / 128), blk, 0, stream>>>(
      xb, wqt, b_qkv, qkb, vTb, C);

  // 2) causal flash attention
  attn_mfma_kernel<<<dim3(BATCH * N_HEADS, SEQ_T / 128), blk, 0, stream>>>(
      qkb, vTb, yb);

  // 3) out = y @ W_proj + b_proj (fp32, swapped order, float4 stores)
  gemm_proj_kernel<<<dim3(8, M / 128), blk, 0, stream>>>(
      yb, wpt, b_proj, out, C, C);
}